// Round 11
// baseline (426.492 us; speedup 1.0000x reference)
//
#include <hip/hip_runtime.h>

// ---------------------------------------------------------------------------
// ConstraintViolationLoss: build x (bf16); sparse Ax via counting-sort with
// FLUSH-TIME cursor reservation (no histogram pass, no scan): block-shared
// LDS write-combining FIFOs flush coalesced bursts at offsets reserved by one
// sharded global atomicAdd per burst, into fixed per-(bucket,shard) regions.
// Overflow (adversarial inputs only) falls back to device atomics on Axg.
// LDS bucket accumulation; fused reduction to 4 scalars.
//
// History: r1/r4 fp32 global atomics = memory-side RMW (scope ignored).
// r2/r5 raw scattered stores = 0.9-1GB write-allocate. r6/r7 block-FIFO WC
// fixes bytes. r9 isolated gather-miss cost -> r10 bf16 x (L2-resident,
// 274us). r11: hist+scan passes (64MB + ~45us) eliminated via flush-time
// sharded cursors; record order within a bucket is irrelevant to the sum.
// ---------------------------------------------------------------------------

#define BSHIFT 14
#define BROWS  (1 << BSHIFT)     // 16384 rows/bucket
#define NBUCK_MAX 32
#define CHUNK 8192               // edges per chunk (one block each)
#define ROUNDS (CHUNK / 1024)    // 8 rounds: 256 threads x 4 edges
#define BUF 192                  // FIFO depth per bucket (block-shared)
#define THRESH 96                // flush threshold
#define SPLIT 8                  // shards = accumulate blocks per bucket

typedef int      iv4 __attribute__((ext_vector_type(4)));
typedef float    fv4 __attribute__((ext_vector_type(4)));
typedef unsigned uv4 __attribute__((ext_vector_type(4)));

__device__ inline unsigned bf16bits(float v) {
    unsigned f = __float_as_uint(v);
    return (f + 0x7FFFu + ((f >> 16) & 1u)) >> 16;   // RNE
}
__device__ inline float bf16val(unsigned bits) {
    return __uint_as_float(bits << 16);
}

// ---------- K1: build-x(bf16) + control zero --------------------------------

__global__ __launch_bounds__(256) void k_build_x(
    const float* __restrict__ prob_bin, const int* __restrict__ idx_bin, int NB, int gBin,
    const float* __restrict__ logits, const float* __restrict__ offs,
    const int* __restrict__ idx_small, int NS, int gSml,
    const float* __restrict__ pred, const int* __restrict__ idx_large, int NL, int gLrg,
    const int* __restrict__ vt, const float* __restrict__ vf, int NV,
    unsigned short* __restrict__ xb, int* __restrict__ ctl, int nctl)
{
    int blk = blockIdx.x, tid = threadIdx.x;
    if (blk == 0)
        for (int i = tid; i < nctl; i += 256) ctl[i] = 0;

    if (blk < gBin) {                         // ---- binary scatter
        int i = blk * 256 + tid;
        if (i < NB) xb[idx_bin[i]] = (unsigned short)bf16bits(prob_bin[i]);
        return;
    }
    blk -= gBin;
    if (blk < gSml) {                         // ---- small-int softmax E[]
        int i = blk * 256 + tid;
        if (i < NS) {
            const fv4* lp = reinterpret_cast<const fv4*>(logits + (size_t)i * 16);
            fv4 v0 = lp[0], v1 = lp[1], v2 = lp[2], v3 = lp[3];
            float l[16] = {v0.x, v0.y, v0.z, v0.w, v1.x, v1.y, v1.z, v1.w,
                           v2.x, v2.y, v2.z, v2.w, v3.x, v3.y, v3.z, v3.w};
            float m = l[0];
#pragma unroll
            for (int j = 1; j < 16; ++j) m = fmaxf(m, l[j]);
            float s = 0.f, ws = 0.f;
#pragma unroll
            for (int j = 0; j < 16; ++j) {
                float e = expf(l[j] - m);
                s += e;
                ws += e * (float)j;
            }
            xb[idx_small[i]] = (unsigned short)bf16bits(ws / s + offs[i]);
        }
        return;
    }
    blk -= gSml;
    if (blk < gLrg) {                         // ---- large-int scatter
        int i = blk * 256 + tid;
        if (i < NL) xb[idx_large[i]] = (unsigned short)bf16bits(pred[i]);
        return;
    }
    blk -= gLrg;
    {                                         // ---- continuous override
        int v = blk * 256 + tid;
        if (v < NV && vt[v] == 0) xb[v] = (unsigned short)bf16bits(vf[(size_t)v * 16 + 8]);
    }
}

// ---- K2: fused scatter: NT streams + bf16 gather + FIFO + flush cursors ----

__global__ __launch_bounds__(256) void k_scatter7(const int* __restrict__ rows,
                                                  const int* __restrict__ cols,
                                                  const float* __restrict__ ef,
                                                  const unsigned short* __restrict__ xb,
                                                  int* __restrict__ gcur8,
                                                  unsigned* __restrict__ recs,
                                                  float* __restrict__ Axg,
                                                  int E, int nbuck, int C8) {
    __shared__ unsigned bufr[NBUCK_MAX][BUF];   // 24KB
    __shared__ int fill[NBUCK_MAX];

    int tid = threadIdx.x, chunk = blockIdx.x, wid = tid >> 6, lane = tid & 63;
    int shard = chunk & (SPLIT - 1);
    if (tid < NBUCK_MAX) fill[tid] = 0;
    __syncthreads();

    int e4max = E >> 2;
    int b4 = chunk * (CHUNK / 4);

    iv4 rA, cA; fv4 fA; bool vA;
    iv4 rB, cB; fv4 fB; bool vB;
    unsigned gA0, gA1, gA2, gA3, gB0, gB1, gB2, gB3;

#define LOADK(k, R, C, F, V)                                                   \
    {   int i4 = b4 + (k) * 256 + tid;                                         \
        V = i4 < e4max;                                                        \
        if (V) {                                                               \
            R = __builtin_nontemporal_load(reinterpret_cast<const iv4*>(rows) + i4); \
            C = __builtin_nontemporal_load(reinterpret_cast<const iv4*>(cols) + i4); \
            F = __builtin_nontemporal_load(reinterpret_cast<const fv4*>(ef) + i4);   \
        } }
#define GATHK(C, V, G0, G1, G2, G3)                                            \
    if (V) { G0 = xb[C.x]; G1 = xb[C.y]; G2 = xb[C.z]; G3 = xb[C.w]; }

    LOADK(0, rA, cA, fA, vA)
    GATHK(cA, vA, gA0, gA1, gA2, gA3)

    for (int k = 0; k < ROUNDS; ++k) {
        if (k + 1 < ROUNDS) {                   // prefetch next round
            LOADK(k + 1, rB, cB, fB, vB)
            GATHK(cB, vB, gB0, gB1, gB2, gB3)
        }
        if (vA) {
            float pf[4] = {fA.x * bf16val(gA0), fA.y * bf16val(gA1),
                           fA.z * bf16val(gA2), fA.w * bf16val(gA3)};
            int ra[4] = {rA.x, rA.y, rA.z, rA.w};
#pragma unroll
            for (int j = 0; j < 4; ++j) {
                int b = ra[j] >> BSHIFT;
                unsigned rec = ((unsigned)(ra[j] & (BROWS - 1)) << 16) | bf16bits(pf[j]);
                int pos = atomicAdd(&fill[b], 1);
                if (pos < BUF) bufr[b][pos] = rec;
                else atomicAdd(&Axg[ra[j]], pf[j]);           // LDS-full fallback (rare)
            }
        }
        if (k == ROUNDS - 1 && chunk == 0 && tid < (E & 3)) { // scalar tail
            int e = (E & ~3) + tid;
            int rrow = rows[e];
            float pv = ef[e] * bf16val(xb[cols[e]]);
            int b = rrow >> BSHIFT;
            unsigned rec = ((unsigned)(rrow & (BROWS - 1)) << 16) | bf16bits(pv);
            int pos = atomicAdd(&fill[b], 1);
            if (pos < BUF) bufr[b][pos] = rec;
            else atomicAdd(&Axg[rrow], pv);
        }
        __syncthreads();
        bool last = (k == ROUNDS - 1);
        for (int b = wid; b < nbuck; b += 4) {  // parallel flush across waves
            int fl = fill[b];
            if (fl == 0) continue;
            if (fl >= THRESH || last) {
                int n = fl < BUF ? fl : BUF;
                int pos;
                if (lane == 0) pos = atomicAdd(&gcur8[b * SPLIT + shard], n);
                pos = __shfl(pos, 0);
                unsigned* reg = recs + (size_t)(b * SPLIT + shard) * C8;
                for (int j = lane; j < n; j += 64) {
                    unsigned rec = bufr[b][j];
                    int idx = pos + j;
                    if (idx < C8)
                        __builtin_nontemporal_store(rec, reg + idx);
                    else                                       // region full (adversarial)
                        atomicAdd(&Axg[(b << BSHIFT) | (int)(rec >> 16)],
                                  bf16val(rec & 0xFFFFu));
                }
                if (lane == 0) fill[b] = 0;
            }
        }
        __syncthreads();
        rA = rB; cA = cB; fA = fB; vA = vB;
        gA0 = gB0; gA1 = gB1; gA2 = gB2; gA3 = gB3;
    }
#undef LOADK
#undef GATHK
}

// -------- K3: LDS bucket accumulate per (bucket, shard) region --------------

__global__ __launch_bounds__(256) void k_accum(const unsigned* __restrict__ recs,
                                               const int* __restrict__ gcur8,
                                               const float* __restrict__ Axg,
                                               float* __restrict__ partial, int C8) {
    __shared__ float tile[BROWS];   // 64KB
    int tid = threadIdx.x;
    int b = blockIdx.x / SPLIT, s = blockIdx.x % SPLIT;
    fv4 z = {0.f, 0.f, 0.f, 0.f};
    for (int i = tid; i < BROWS / 4; i += 256) reinterpret_cast<fv4*>(tile)[i] = z;
    __syncthreads();
    int len = gcur8[b * SPLIT + s];
    if (len > C8) len = C8;
    const unsigned* rp = recs + (size_t)(b * SPLIT + s) * C8;
    for (int i = tid << 2; i + 3 < len; i += 1024) {
        uv4 r = __builtin_nontemporal_load(reinterpret_cast<const uv4*>(rp + i));
        atomicAdd(&tile[r.x >> 16], __uint_as_float((r.x & 0xFFFFu) << 16));
        atomicAdd(&tile[r.y >> 16], __uint_as_float((r.y & 0xFFFFu) << 16));
        atomicAdd(&tile[r.z >> 16], __uint_as_float((r.z & 0xFFFFu) << 16));
        atomicAdd(&tile[r.w >> 16], __uint_as_float((r.w & 0xFFFFu) << 16));
    }
    if (tid < (len & 3)) {                     // <=3 tail records
        unsigned rr = rp[(len & ~3) + tid];
        atomicAdd(&tile[rr >> 16], __uint_as_float((rr & 0xFFFFu) << 16));
    }
    __syncthreads();
    if (s == 0) {                              // fold overflow accumulator once
        const float* ax = Axg + ((size_t)b << BSHIFT);
        for (int i = tid; i < BROWS; i += 256) tile[i] += ax[i];
    }
    __syncthreads();
    float* out = partial + ((size_t)blockIdx.x << BSHIFT);
    for (int j = tid; j < BROWS / 4; j += 256)
        __builtin_nontemporal_store(reinterpret_cast<const fv4*>(tile)[j],
                                    reinterpret_cast<fv4*>(out) + j);
}

// ------- K4: fold partials + bias + relu + reduce + ticketed finalize -------

__global__ __launch_bounds__(256) void k_reduce_fin(const float* __restrict__ partial,
                                                    const float* __restrict__ cf,
                                                    float* __restrict__ acc,
                                                    float* __restrict__ out,
                                                    int ncon, int nblocks) {
    float lsum = 0.f, lmax = 0.f;
    unsigned lcnt = 0;
    int stride = gridDim.x * blockDim.x;
    for (int c = blockIdx.x * blockDim.x + threadIdx.x; c < ncon; c += stride) {
        int b = c >> BSHIFT, i = c & (BROWS - 1);
        const float* p = partial + (((size_t)b * SPLIT) << BSHIFT) + i;
        float v = 0.f;
#pragma unroll
        for (int s = 0; s < SPLIT; ++s)
            v += __builtin_nontemporal_load(p + ((size_t)s << BSHIFT));
        v -= cf[(size_t)c * 8 + 1];
        v = v > 0.f ? v : 0.f;
        lsum += v;
        lmax = fmaxf(lmax, v);
        lcnt += (v > 1e-6f) ? 1u : 0u;
    }
#pragma unroll
    for (int o = 32; o > 0; o >>= 1) {
        lsum += __shfl_down(lsum, o);
        lmax = fmaxf(lmax, __shfl_down(lmax, o));
        lcnt += __shfl_down(lcnt, o);
    }
    __shared__ float ssum[4];
    __shared__ float smax[4];
    __shared__ unsigned scnt[4];
    int lane = threadIdx.x & 63, wid = threadIdx.x >> 6;
    if (lane == 0) { ssum[wid] = lsum; smax[wid] = lmax; scnt[wid] = lcnt; }
    __syncthreads();
    if (threadIdx.x == 0) {
        float bs = 0.f, bm = 0.f;
        unsigned bc = 0;
        for (int w = 0; w < 4; ++w) { bs += ssum[w]; bm = fmaxf(bm, smax[w]); bc += scnt[w]; }
        atomicAdd(&acc[0], bs);
        atomicMax(reinterpret_cast<unsigned*>(acc) + 1, __float_as_uint(bm));
        atomicAdd(reinterpret_cast<unsigned*>(acc) + 2, bc);
        __threadfence();
        unsigned t = atomicAdd(reinterpret_cast<unsigned*>(acc) + 3, 1u);
        if (t == (unsigned)(nblocks - 1)) {
            float sum   = atomicAdd(&acc[0], 0.f);
            unsigned mb = atomicMax(reinterpret_cast<unsigned*>(acc) + 1, 0u);
            unsigned ct = atomicAdd(reinterpret_cast<unsigned*>(acc) + 2, 0u);
            float mean = sum / (float)ncon;
            float mx = __uint_as_float(mb);
            out[0] = mean + 0.1f * mx;
            out[1] = mean;
            out[2] = mx;
            out[3] = (float)ct;
        }
    }
}

// ------------------- fallback: direct device-scope atomics ------------------

__global__ void k_edges(const float* __restrict__ ef, const int* __restrict__ rows,
                        const int* __restrict__ cols, const unsigned short* __restrict__ xb,
                        float* __restrict__ Ax, int e4, int E) {
    int stride = gridDim.x * blockDim.x;
    int gid = blockIdx.x * blockDim.x + threadIdx.x;
    for (int i = gid; i < e4; i += stride) {
        fv4 f = reinterpret_cast<const fv4*>(ef)[i];
        iv4 r = reinterpret_cast<const iv4*>(rows)[i];
        iv4 c = reinterpret_cast<const iv4*>(cols)[i];
        atomicAdd(&Ax[r.x], f.x * bf16val(xb[c.x]));
        atomicAdd(&Ax[r.y], f.y * bf16val(xb[c.y]));
        atomicAdd(&Ax[r.z], f.z * bf16val(xb[c.z]));
        atomicAdd(&Ax[r.w], f.w * bf16val(xb[c.w]));
    }
    for (int e = e4 * 4 + gid; e < E; e += stride)
        atomicAdd(&Ax[rows[e]], ef[e] * bf16val(xb[cols[e]]));
}

__global__ void k_reduce_ax(const float* __restrict__ Ax, const float* __restrict__ cf,
                            float* __restrict__ acc, float* __restrict__ out,
                            int ncon, int nblocks) {
    float lsum = 0.f, lmax = 0.f;
    unsigned lcnt = 0;
    int stride = gridDim.x * blockDim.x;
    for (int c = blockIdx.x * blockDim.x + threadIdx.x; c < ncon; c += stride) {
        float v = Ax[c] - cf[(size_t)c * 8 + 1];
        v = v > 0.f ? v : 0.f;
        lsum += v;
        lmax = fmaxf(lmax, v);
        lcnt += (v > 1e-6f) ? 1u : 0u;
    }
#pragma unroll
    for (int o = 32; o > 0; o >>= 1) {
        lsum += __shfl_down(lsum, o);
        lmax = fmaxf(lmax, __shfl_down(lmax, o));
        lcnt += __shfl_down(lcnt, o);
    }
    __shared__ float ssum[4];
    __shared__ float smax[4];
    __shared__ unsigned scnt[4];
    int lane = threadIdx.x & 63, wid = threadIdx.x >> 6;
    if (lane == 0) { ssum[wid] = lsum; smax[wid] = lmax; scnt[wid] = lcnt; }
    __syncthreads();
    if (threadIdx.x == 0) {
        float bs = 0.f, bm = 0.f;
        unsigned bc = 0;
        for (int w = 0; w < 4; ++w) { bs += ssum[w]; bm = fmaxf(bm, smax[w]); bc += scnt[w]; }
        atomicAdd(&acc[0], bs);
        atomicMax(reinterpret_cast<unsigned*>(acc) + 1, __float_as_uint(bm));
        atomicAdd(reinterpret_cast<unsigned*>(acc) + 2, bc);
        __threadfence();
        unsigned t = atomicAdd(reinterpret_cast<unsigned*>(acc) + 3, 1u);
        if (t == (unsigned)(nblocks - 1)) {
            float sum   = atomicAdd(&acc[0], 0.f);
            unsigned mb = atomicMax(reinterpret_cast<unsigned*>(acc) + 1, 0u);
            unsigned ct = atomicAdd(reinterpret_cast<unsigned*>(acc) + 2, 0u);
            float mean = sum / (float)ncon;
            float mx = __uint_as_float(mb);
            out[0] = mean + 0.1f * mx;
            out[1] = mean;
            out[2] = mx;
            out[3] = (float)ct;
        }
    }
}

// ------------------------------ launcher -----------------------------------

extern "C" void kernel_launch(void* const* d_in, const int* in_sizes, int n_in,
                              void* d_out, int out_size, void* d_ws, size_t ws_size,
                              hipStream_t stream) {
    const float* prob_bin     = (const float*)d_in[0];
    const float* logits_small = (const float*)d_in[1];
    const float* offs_small   = (const float*)d_in[2];
    const float* pred_large   = (const float*)d_in[3];
    const float* edge_feat    = (const float*)d_in[4];
    const float* cons_feat    = (const float*)d_in[5];
    const float* var_feat     = (const float*)d_in[6];
    const int*   idx_bin      = (const int*)d_in[7];
    const int*   idx_small    = (const int*)d_in[8];
    const int*   idx_large    = (const int*)d_in[9];
    const int*   var_types    = (const int*)d_in[10];
    const int*   edge_indices = (const int*)d_in[11];

    const int NB    = in_sizes[0];
    const int NS    = in_sizes[2];
    const int NL    = in_sizes[3];
    const int E     = in_sizes[4];
    const int NCON  = in_sizes[5] / 8;
    const int NVARS = in_sizes[10];

    const int* rows = edge_indices;
    const int* cols = edge_indices + E;

    const int nbuck   = (NCON + BROWS - 1) >> BSHIFT;
    const int nchunks = (E + CHUNK - 1) / CHUNK;

    // per-(bucket,shard) region capacity: 1.5x expected, multiple of 4
    int c8 = (nbuck > 0) ? (int)(((long long)E * 3) / (2LL * nbuck * SPLIT)) : 0;
    c8 = (c8 + 1024 + 3) & ~3;

    // ws layout (256B-aligned): xb | recs | partial | Axg | ctl(gcur8[256]+acc[4])
    char* w = (char*)d_ws;
    size_t o = 0;
    auto take = [&](size_t bytes) -> char* {
        char* p = w + o;
        o = (o + bytes + 255) & ~(size_t)255;
        return p;
    };
    unsigned short* xb = (unsigned short*)take((size_t)NVARS * 2);
    unsigned* recs     = (unsigned*)take((size_t)nbuck * SPLIT * c8 * 4);
    float*    partial  = (float*)take((size_t)nbuck * SPLIT * BROWS * 4);
    float*    Axg      = (float*)take((size_t)nbuck * BROWS * 4);
    int*      ctl      = (int*)take((NBUCK_MAX * SPLIT + 4) * 4);
    size_t need = o;

    int*   gcur8 = ctl;
    float* acc   = (float*)(ctl + NBUCK_MAX * SPLIT);
    const int NCTL = NBUCK_MAX * SPLIT + 4;

    const int B = 256;
    bool sorted_path = (ws_size >= need) && (nbuck <= NBUCK_MAX);

    const int gBin = (NB + B - 1) / B;
    const int gSml = (NS + B - 1) / B;
    const int gLrg = (NL + B - 1) / B;
    const int gCnt = (NVARS + B - 1) / B;

    if (sorted_path) {
        (void)hipMemsetAsync(Axg, 0, (size_t)nbuck * BROWS * 4, stream);
        k_build_x<<<gBin + gSml + gLrg + gCnt, B, 0, stream>>>(
            prob_bin, idx_bin, NB, gBin,
            logits_small, offs_small, idx_small, NS, gSml,
            pred_large, idx_large, NL, gLrg,
            var_types, var_feat, NVARS, xb, ctl, NCTL);
        k_scatter7<<<nchunks, B, 0, stream>>>(rows, cols, edge_feat, xb, gcur8,
                                              recs, Axg, E, nbuck, c8);
        k_accum<<<nbuck * SPLIT, B, 0, stream>>>(recs, gcur8, Axg, partial, c8);
        const int rblocks = 1024;
        k_reduce_fin<<<rblocks, B, 0, stream>>>(partial, cons_feat, acc, (float*)d_out,
                                                NCON, rblocks);
    } else {
        // fallback: direct device-scope atomics (xb + acc + Ax)
        float* accf = (float*)((char*)d_ws + (((size_t)NVARS * 2 + 255) & ~(size_t)255));
        float* Ax   = accf + 8;
        (void)hipMemsetAsync(accf, 0, (size_t)(8 + NCON) * sizeof(float), stream);
        k_build_x<<<gBin + gSml + gLrg + gCnt, B, 0, stream>>>(
            prob_bin, idx_bin, NB, gBin,
            logits_small, offs_small, idx_small, NS, gSml,
            pred_large, idx_large, NL, gLrg,
            var_types, var_feat, NVARS, xb, (int*)accf, 4);
        k_edges<<<2048, B, 0, stream>>>(edge_feat, rows, cols, xb, Ax, E / 4, E);
        k_reduce_ax<<<1024, B, 0, stream>>>(Ax, cons_feat, accf, (float*)d_out, NCON, 1024);
    }
}

// Round 12
// 344.655 us; speedup vs baseline: 1.2374x; 1.2374x over previous
//
#include <hip/hip_runtime.h>

// ---------------------------------------------------------------------------
// ConstraintViolationLoss: build x (bf16); sparse Ax via LDS write-combining
// FIFO scatter with PARALLEL flush-time cursor reservation (no histogram, no
// scan): at each round barrier, lanes tid<32 reserve flush space for ALL
// buckets concurrently (one predicated global atomicAdd each -> single hidden
// latency), broadcast pos via LDS, then all waves flush r10-style bursts.
// Overflow -> device atomics on zeroed Axg (folded in accum). LDS bucket
// accumulation; fused reduction to [penalty, mean_viol, max_viol, n_viol].
//
// History: r1/r4 fp32 global atomics = memory-side RMW (scope ignored).
// r2/r5 raw scattered stores = 0.9-1GB write-allocate. r6/r7 block-FIFO WC
// fixes bytes. r10 bf16 x = L2-resident gather (274us, scatter 110).
// r11 regressed (269us scatter): cursor atomics SEQUENTIAL per wave.
// r12: same cursors, reserved in parallel by 32 lanes at the barrier.
// ---------------------------------------------------------------------------

#define BSHIFT 14
#define BROWS  (1 << BSHIFT)     // 16384 rows/bucket
#define NBUCK_MAX 32
#define CHUNK 8192               // edges per chunk (one block each)
#define ROUNDS (CHUNK / 1024)    // 8 rounds: 256 threads x 4 edges
#define BUF 128                  // FIFO depth per bucket (block-shared)
#define THRESH 48                // flush threshold
#define SPLIT 8                  // shards = accumulate blocks per bucket

typedef int      iv4 __attribute__((ext_vector_type(4)));
typedef float    fv4 __attribute__((ext_vector_type(4)));
typedef unsigned uv4 __attribute__((ext_vector_type(4)));

__device__ inline unsigned bf16bits(float v) {
    unsigned f = __float_as_uint(v);
    return (f + 0x7FFFu + ((f >> 16) & 1u)) >> 16;   // RNE
}
__device__ inline float bf16val(unsigned bits) {
    return __uint_as_float(bits << 16);
}

// ---------- K1: build-x(bf16) + control zero --------------------------------

__global__ __launch_bounds__(256) void k_build_x(
    const float* __restrict__ prob_bin, const int* __restrict__ idx_bin, int NB, int gBin,
    const float* __restrict__ logits, const float* __restrict__ offs,
    const int* __restrict__ idx_small, int NS, int gSml,
    const float* __restrict__ pred, const int* __restrict__ idx_large, int NL, int gLrg,
    const int* __restrict__ vt, const float* __restrict__ vf, int NV,
    unsigned short* __restrict__ xb, int* __restrict__ ctl, int nctl)
{
    int blk = blockIdx.x, tid = threadIdx.x;
    if (blk == 0)
        for (int i = tid; i < nctl; i += 256) ctl[i] = 0;

    if (blk < gBin) {                         // ---- binary scatter
        int i = blk * 256 + tid;
        if (i < NB) xb[idx_bin[i]] = (unsigned short)bf16bits(prob_bin[i]);
        return;
    }
    blk -= gBin;
    if (blk < gSml) {                         // ---- small-int softmax E[]
        int i = blk * 256 + tid;
        if (i < NS) {
            const fv4* lp = reinterpret_cast<const fv4*>(logits + (size_t)i * 16);
            fv4 v0 = lp[0], v1 = lp[1], v2 = lp[2], v3 = lp[3];
            float l[16] = {v0.x, v0.y, v0.z, v0.w, v1.x, v1.y, v1.z, v1.w,
                           v2.x, v2.y, v2.z, v2.w, v3.x, v3.y, v3.z, v3.w};
            float m = l[0];
#pragma unroll
            for (int j = 1; j < 16; ++j) m = fmaxf(m, l[j]);
            float s = 0.f, ws = 0.f;
#pragma unroll
            for (int j = 0; j < 16; ++j) {
                float e = expf(l[j] - m);
                s += e;
                ws += e * (float)j;
            }
            xb[idx_small[i]] = (unsigned short)bf16bits(ws / s + offs[i]);
        }
        return;
    }
    blk -= gSml;
    if (blk < gLrg) {                         // ---- large-int scatter
        int i = blk * 256 + tid;
        if (i < NL) xb[idx_large[i]] = (unsigned short)bf16bits(pred[i]);
        return;
    }
    blk -= gLrg;
    {                                         // ---- continuous override
        int v = blk * 256 + tid;
        if (v < NV && vt[v] == 0) xb[v] = (unsigned short)bf16bits(vf[(size_t)v * 16 + 8]);
    }
}

// ---- K2: scatter: NT streams + bf16 gather + FIFO + parallel reservation ---

__global__ __launch_bounds__(256) void k_scatter8(const int* __restrict__ rows,
                                                  const int* __restrict__ cols,
                                                  const float* __restrict__ ef,
                                                  const unsigned short* __restrict__ xb,
                                                  int* __restrict__ gcur,
                                                  unsigned* __restrict__ recs,
                                                  float* __restrict__ Axg,
                                                  int E, int nbuck, int C8) {
    __shared__ unsigned bufr[NBUCK_MAX][BUF];   // 16KB
    __shared__ int fill[NBUCK_MAX];
    __shared__ int posb[NBUCK_MAX];
    __shared__ int n4b[NBUCK_MAX];

    int tid = threadIdx.x, chunk = blockIdx.x, wid = tid >> 6, lane = tid & 63;
    int shard = chunk & (SPLIT - 1);
    if (tid < NBUCK_MAX) fill[tid] = 0;
    __syncthreads();

    int e4max = E >> 2;
    int b4 = chunk * (CHUNK / 4);

    iv4 rA, cA; fv4 fA; bool vA;
    iv4 rB, cB; fv4 fB; bool vB;
    unsigned gA0, gA1, gA2, gA3, gB0, gB1, gB2, gB3;

#define LOADK(k, R, C, F, V)                                                   \
    {   int i4 = b4 + (k) * 256 + tid;                                         \
        V = i4 < e4max;                                                        \
        if (V) {                                                               \
            R = __builtin_nontemporal_load(reinterpret_cast<const iv4*>(rows) + i4); \
            C = __builtin_nontemporal_load(reinterpret_cast<const iv4*>(cols) + i4); \
            F = __builtin_nontemporal_load(reinterpret_cast<const fv4*>(ef) + i4);   \
        } }
#define GATHK(C, V, G0, G1, G2, G3)                                            \
    if (V) { G0 = xb[C.x]; G1 = xb[C.y]; G2 = xb[C.z]; G3 = xb[C.w]; }

    LOADK(0, rA, cA, fA, vA)
    GATHK(cA, vA, gA0, gA1, gA2, gA3)

    for (int k = 0; k < ROUNDS; ++k) {
        if (k + 1 < ROUNDS) {                   // prefetch next round
            LOADK(k + 1, rB, cB, fB, vB)
            GATHK(cB, vB, gB0, gB1, gB2, gB3)
        }
        if (vA) {
            float pf[4] = {fA.x * bf16val(gA0), fA.y * bf16val(gA1),
                           fA.z * bf16val(gA2), fA.w * bf16val(gA3)};
            int ra[4] = {rA.x, rA.y, rA.z, rA.w};
#pragma unroll
            for (int j = 0; j < 4; ++j) {
                int b = ra[j] >> BSHIFT;
                unsigned rec = ((unsigned)(ra[j] & (BROWS - 1)) << 16) | bf16bits(pf[j]);
                int pos = atomicAdd(&fill[b], 1);
                if (pos < BUF) bufr[b][pos] = rec;
                else atomicAdd(&Axg[ra[j]], pf[j]);           // FIFO-full fallback (rare)
            }
        }
        if (k == ROUNDS - 1 && chunk == 0 && tid < (E & 3)) { // scalar tail
            int e = (E & ~3) + tid;
            int rrow = rows[e];
            float pv = ef[e] * bf16val(xb[cols[e]]);
            int b = rrow >> BSHIFT;
            unsigned rec = ((unsigned)(rrow & (BROWS - 1)) << 16) | bf16bits(pv);
            int pos = atomicAdd(&fill[b], 1);
            if (pos < BUF) bufr[b][pos] = rec;
            else atomicAdd(&Axg[rrow], pv);
        }
        __syncthreads();
        bool last = (k == ROUNDS - 1);
        if (tid < NBUCK_MAX) {                  // PARALLEL reservation, 32 lanes
            int b = tid;
            int n = 0;
            if (b < nbuck) {
                int fl = fill[b];
                if (fl >= THRESH || (last && fl > 0)) {
                    n = fl < BUF ? fl : BUF;
                    fill[b] = 0;
                }
            }
            n4b[b] = n;
            posb[b] = n ? atomicAdd(&gcur[b * SPLIT + shard], n) : 0;
        }
        __syncthreads();
        for (int b = wid; b < nbuck; b += 4) {  // parallel flush across waves
            int n = n4b[b];
            if (n == 0) continue;
            int pos = posb[b];
            unsigned* reg = recs + (size_t)(b * SPLIT + shard) * C8;
            for (int j = lane; j < n; j += 64) {
                unsigned rec = bufr[b][j];
                int idx = pos + j;
                if (idx < C8)
                    __builtin_nontemporal_store(rec, reg + idx);
                else                                           // region full (adversarial)
                    atomicAdd(&Axg[(b << BSHIFT) | (int)(rec >> 16)],
                              bf16val(rec & 0xFFFFu));
            }
        }
        __syncthreads();
        rA = rB; cA = cB; fA = fB; vA = vB;
        gA0 = gB0; gA1 = gB1; gA2 = gB2; gA3 = gB3;
    }
#undef LOADK
#undef GATHK
}

// -------- K3: LDS bucket accumulate per (bucket, shard) region --------------

__global__ __launch_bounds__(256) void k_accum(const unsigned* __restrict__ recs,
                                               const int* __restrict__ gcur,
                                               const float* __restrict__ Axg,
                                               float* __restrict__ partial, int C8) {
    __shared__ float tile[BROWS];   // 64KB
    int tid = threadIdx.x;
    int b = blockIdx.x / SPLIT, s = blockIdx.x % SPLIT;
    fv4 z = {0.f, 0.f, 0.f, 0.f};
    for (int i = tid; i < BROWS / 4; i += 256) reinterpret_cast<fv4*>(tile)[i] = z;
    __syncthreads();
    int len = gcur[b * SPLIT + s];
    if (len > C8) len = C8;
    const unsigned* rp = recs + (size_t)(b * SPLIT + s) * C8;
    for (int i = tid << 2; i + 3 < len; i += 1024) {
        uv4 r = __builtin_nontemporal_load(reinterpret_cast<const uv4*>(rp + i));
        atomicAdd(&tile[r.x >> 16], __uint_as_float((r.x & 0xFFFFu) << 16));
        atomicAdd(&tile[r.y >> 16], __uint_as_float((r.y & 0xFFFFu) << 16));
        atomicAdd(&tile[r.z >> 16], __uint_as_float((r.z & 0xFFFFu) << 16));
        atomicAdd(&tile[r.w >> 16], __uint_as_float((r.w & 0xFFFFu) << 16));
    }
    if (tid < (len & 3)) {                     // <=3 tail records
        unsigned rr = rp[(len & ~3) + tid];
        atomicAdd(&tile[rr >> 16], __uint_as_float((rr & 0xFFFFu) << 16));
    }
    __syncthreads();
    if (s == 0) {                              // fold overflow accumulator once
        const float* ax = Axg + ((size_t)b << BSHIFT);
        for (int i = tid; i < BROWS; i += 256) tile[i] += ax[i];
    }
    __syncthreads();
    float* out = partial + ((size_t)blockIdx.x << BSHIFT);
    for (int j = tid; j < BROWS / 4; j += 256)
        __builtin_nontemporal_store(reinterpret_cast<const fv4*>(tile)[j],
                                    reinterpret_cast<fv4*>(out) + j);
}

// ------- K4: fold partials + bias + relu + reduce + ticketed finalize -------

__global__ __launch_bounds__(256) void k_reduce_fin(const float* __restrict__ partial,
                                                    const float* __restrict__ cf,
                                                    float* __restrict__ acc,
                                                    float* __restrict__ out,
                                                    int ncon, int nblocks) {
    float lsum = 0.f, lmax = 0.f;
    unsigned lcnt = 0;
    int stride = gridDim.x * blockDim.x;
    for (int c = blockIdx.x * blockDim.x + threadIdx.x; c < ncon; c += stride) {
        int b = c >> BSHIFT, i = c & (BROWS - 1);
        const float* p = partial + (((size_t)b * SPLIT) << BSHIFT) + i;
        float v = 0.f;
#pragma unroll
        for (int s = 0; s < SPLIT; ++s)
            v += __builtin_nontemporal_load(p + ((size_t)s << BSHIFT));
        v -= cf[(size_t)c * 8 + 1];
        v = v > 0.f ? v : 0.f;
        lsum += v;
        lmax = fmaxf(lmax, v);
        lcnt += (v > 1e-6f) ? 1u : 0u;
    }
#pragma unroll
    for (int o = 32; o > 0; o >>= 1) {
        lsum += __shfl_down(lsum, o);
        lmax = fmaxf(lmax, __shfl_down(lmax, o));
        lcnt += __shfl_down(lcnt, o);
    }
    __shared__ float ssum[4];
    __shared__ float smax[4];
    __shared__ unsigned scnt[4];
    int lane = threadIdx.x & 63, wid = threadIdx.x >> 6;
    if (lane == 0) { ssum[wid] = lsum; smax[wid] = lmax; scnt[wid] = lcnt; }
    __syncthreads();
    if (threadIdx.x == 0) {
        float bs = 0.f, bm = 0.f;
        unsigned bc = 0;
        for (int w = 0; w < 4; ++w) { bs += ssum[w]; bm = fmaxf(bm, smax[w]); bc += scnt[w]; }
        atomicAdd(&acc[0], bs);
        atomicMax(reinterpret_cast<unsigned*>(acc) + 1, __float_as_uint(bm));
        atomicAdd(reinterpret_cast<unsigned*>(acc) + 2, bc);
        __threadfence();
        unsigned t = atomicAdd(reinterpret_cast<unsigned*>(acc) + 3, 1u);
        if (t == (unsigned)(nblocks - 1)) {
            float sum   = atomicAdd(&acc[0], 0.f);
            unsigned mb = atomicMax(reinterpret_cast<unsigned*>(acc) + 1, 0u);
            unsigned ct = atomicAdd(reinterpret_cast<unsigned*>(acc) + 2, 0u);
            float mean = sum / (float)ncon;
            float mx = __uint_as_float(mb);
            out[0] = mean + 0.1f * mx;
            out[1] = mean;
            out[2] = mx;
            out[3] = (float)ct;
        }
    }
}

// ------------------- fallback: direct device-scope atomics ------------------

__global__ void k_edges(const float* __restrict__ ef, const int* __restrict__ rows,
                        const int* __restrict__ cols, const unsigned short* __restrict__ xb,
                        float* __restrict__ Ax, int e4, int E) {
    int stride = gridDim.x * blockDim.x;
    int gid = blockIdx.x * blockDim.x + threadIdx.x;
    for (int i = gid; i < e4; i += stride) {
        fv4 f = reinterpret_cast<const fv4*>(ef)[i];
        iv4 r = reinterpret_cast<const iv4*>(rows)[i];
        iv4 c = reinterpret_cast<const iv4*>(cols)[i];
        atomicAdd(&Ax[r.x], f.x * bf16val(xb[c.x]));
        atomicAdd(&Ax[r.y], f.y * bf16val(xb[c.y]));
        atomicAdd(&Ax[r.z], f.z * bf16val(xb[c.z]));
        atomicAdd(&Ax[r.w], f.w * bf16val(xb[c.w]));
    }
    for (int e = e4 * 4 + gid; e < E; e += stride)
        atomicAdd(&Ax[rows[e]], ef[e] * bf16val(xb[cols[e]]));
}

__global__ void k_reduce_ax(const float* __restrict__ Ax, const float* __restrict__ cf,
                            float* __restrict__ acc, float* __restrict__ out,
                            int ncon, int nblocks) {
    float lsum = 0.f, lmax = 0.f;
    unsigned lcnt = 0;
    int stride = gridDim.x * blockDim.x;
    for (int c = blockIdx.x * blockDim.x + threadIdx.x; c < ncon; c += stride) {
        float v = Ax[c] - cf[(size_t)c * 8 + 1];
        v = v > 0.f ? v : 0.f;
        lsum += v;
        lmax = fmaxf(lmax, v);
        lcnt += (v > 1e-6f) ? 1u : 0u;
    }
#pragma unroll
    for (int o = 32; o > 0; o >>= 1) {
        lsum += __shfl_down(lsum, o);
        lmax = fmaxf(lmax, __shfl_down(lmax, o));
        lcnt += __shfl_down(lcnt, o);
    }
    __shared__ float ssum[4];
    __shared__ float smax[4];
    __shared__ unsigned scnt[4];
    int lane = threadIdx.x & 63, wid = threadIdx.x >> 6;
    if (lane == 0) { ssum[wid] = lsum; smax[wid] = lmax; scnt[wid] = lcnt; }
    __syncthreads();
    if (threadIdx.x == 0) {
        float bs = 0.f, bm = 0.f;
        unsigned bc = 0;
        for (int w = 0; w < 4; ++w) { bs += ssum[w]; bm = fmaxf(bm, smax[w]); bc += scnt[w]; }
        atomicAdd(&acc[0], bs);
        atomicMax(reinterpret_cast<unsigned*>(acc) + 1, __float_as_uint(bm));
        atomicAdd(reinterpret_cast<unsigned*>(acc) + 2, bc);
        __threadfence();
        unsigned t = atomicAdd(reinterpret_cast<unsigned*>(acc) + 3, 1u);
        if (t == (unsigned)(nblocks - 1)) {
            float sum   = atomicAdd(&acc[0], 0.f);
            unsigned mb = atomicMax(reinterpret_cast<unsigned*>(acc) + 1, 0u);
            unsigned ct = atomicAdd(reinterpret_cast<unsigned*>(acc) + 2, 0u);
            float mean = sum / (float)ncon;
            float mx = __uint_as_float(mb);
            out[0] = mean + 0.1f * mx;
            out[1] = mean;
            out[2] = mx;
            out[3] = (float)ct;
        }
    }
}

// ------------------------------ launcher -----------------------------------

extern "C" void kernel_launch(void* const* d_in, const int* in_sizes, int n_in,
                              void* d_out, int out_size, void* d_ws, size_t ws_size,
                              hipStream_t stream) {
    const float* prob_bin     = (const float*)d_in[0];
    const float* logits_small = (const float*)d_in[1];
    const float* offs_small   = (const float*)d_in[2];
    const float* pred_large   = (const float*)d_in[3];
    const float* edge_feat    = (const float*)d_in[4];
    const float* cons_feat    = (const float*)d_in[5];
    const float* var_feat     = (const float*)d_in[6];
    const int*   idx_bin      = (const int*)d_in[7];
    const int*   idx_small    = (const int*)d_in[8];
    const int*   idx_large    = (const int*)d_in[9];
    const int*   var_types    = (const int*)d_in[10];
    const int*   edge_indices = (const int*)d_in[11];

    const int NB    = in_sizes[0];
    const int NS    = in_sizes[2];
    const int NL    = in_sizes[3];
    const int E     = in_sizes[4];
    const int NCON  = in_sizes[5] / 8;
    const int NVARS = in_sizes[10];

    const int* rows = edge_indices;
    const int* cols = edge_indices + E;

    const int nbuck   = (NCON + BROWS - 1) >> BSHIFT;
    const int nchunks = (E + CHUNK - 1) / CHUNK;

    // per-(bucket,shard) region capacity: 1.5x expected + slack, multiple of 4
    int c8 = (nbuck > 0) ? (int)(((long long)E * 3) / (2LL * nbuck * SPLIT)) : 0;
    c8 = (c8 + 1024 + 3) & ~3;

    // ws layout (256B-aligned): xb | recs | partial | Axg | ctl(gcur[256]+acc[4])
    char* w = (char*)d_ws;
    size_t o = 0;
    auto take = [&](size_t bytes) -> char* {
        char* p = w + o;
        o = (o + bytes + 255) & ~(size_t)255;
        return p;
    };
    unsigned short* xb = (unsigned short*)take((size_t)NVARS * 2);
    unsigned* recs     = (unsigned*)take((size_t)nbuck * SPLIT * c8 * 4);
    float*    partial  = (float*)take((size_t)nbuck * SPLIT * BROWS * 4);
    float*    Axg      = (float*)take((size_t)nbuck * BROWS * 4);
    int*      ctl      = (int*)take((NBUCK_MAX * SPLIT + 4) * 4);
    size_t need = o;

    int*   gcur = ctl;
    float* acc  = (float*)(ctl + NBUCK_MAX * SPLIT);
    const int NCTL = NBUCK_MAX * SPLIT + 4;

    const int B = 256;
    bool sorted_path = (ws_size >= need) && (nbuck <= NBUCK_MAX);

    const int gBin = (NB + B - 1) / B;
    const int gSml = (NS + B - 1) / B;
    const int gLrg = (NL + B - 1) / B;
    const int gCnt = (NVARS + B - 1) / B;

    if (sorted_path) {
        (void)hipMemsetAsync(Axg, 0, (size_t)nbuck * BROWS * 4, stream);
        k_build_x<<<gBin + gSml + gLrg + gCnt, B, 0, stream>>>(
            prob_bin, idx_bin, NB, gBin,
            logits_small, offs_small, idx_small, NS, gSml,
            pred_large, idx_large, NL, gLrg,
            var_types, var_feat, NVARS, xb, ctl, NCTL);
        k_scatter8<<<nchunks, B, 0, stream>>>(rows, cols, edge_feat, xb, gcur,
                                              recs, Axg, E, nbuck, c8);
        k_accum<<<nbuck * SPLIT, B, 0, stream>>>(recs, gcur, Axg, partial, c8);
        const int rblocks = 1024;
        k_reduce_fin<<<rblocks, B, 0, stream>>>(partial, cons_feat, acc, (float*)d_out,
                                                NCON, rblocks);
    } else {
        // fallback: direct device-scope atomics (xb + acc + Ax)
        float* accf = (float*)((char*)d_ws + (((size_t)NVARS * 2 + 255) & ~(size_t)255));
        float* Ax   = accf + 8;
        (void)hipMemsetAsync(accf, 0, (size_t)(8 + NCON) * sizeof(float), stream);
        k_build_x<<<gBin + gSml + gLrg + gCnt, B, 0, stream>>>(
            prob_bin, idx_bin, NB, gBin,
            logits_small, offs_small, idx_small, NS, gSml,
            pred_large, idx_large, NL, gLrg,
            var_types, var_feat, NVARS, xb, (int*)accf, 4);
        k_edges<<<2048, B, 0, stream>>>(edge_feat, rows, cols, xb, Ax, E / 4, E);
        k_reduce_ax<<<1024, B, 0, stream>>>(Ax, cons_feat, accf, (float*)d_out, NCON, 1024);
    }
}